// Round 21
// baseline (182.499 us; speedup 1.0000x reference)
//
#include <hip/hip_runtime.h>
#include <cfloat>

#define NN 50000
#define EE 1600000
#define NEG 0.2f
#define BSH 7
#define BSZ 128                       // nodes per bucket
#define NBK ((NN + BSZ - 1) / BSZ)    // 391
#define CAPB 4608                     // fixed bucket capacity (mean 4096 + 8 sigma)
#define TSZ 8192                      // k_bin tile size (edges)
#define NT  ((EE + TSZ - 1) / TSZ)    // 196 tiles per list
#define NTILE (NN / 16)               // 3125 gemm tiles
#define GEMM_BLKS ((NTILE + 7) / 8)   // 391 (8 tiles per 512-thr block)

typedef __attribute__((ext_vector_type(8))) short short8;
typedef __attribute__((ext_vector_type(4))) float f32x4;
typedef __attribute__((ext_vector_type(2))) float f32x2;

__device__ inline float leaky(float v) { return fmaxf(v, NEG * v); }

__device__ inline unsigned short f2bf(float f) {
    unsigned u = __float_as_uint(f);
    u += 0x7FFFu + ((u >> 16) & 1u);          // round-to-nearest-even
    return (unsigned short)(u >> 16);
}
__device__ inline float bf2f(unsigned short s) {
    return __uint_as_float(((unsigned)s) << 16);
}

// f32 -> e4m3fn (RNE; tiny values flushed to +-2^-6 so decode is branch-free)
__device__ inline unsigned f2e4m3(float f) {
    unsigned u = __float_as_uint(f);
    unsigned s = (u >> 24) & 0x80u;
    unsigned t = u + 0x7FFFFu + ((u >> 20) & 1u);
    int e = (int)((t >> 23) & 0xFFu) - 120;
    if (e < 1)  return s | 0x08u;             // +-2^-6
    if (e > 15) return s | 0x7Fu;             // clamp (unreachable for |h|<3.5)
    return s | ((unsigned)e << 3) | ((t >> 20) & 7u);
}
__device__ inline float e4m3f(unsigned b) {   // b in [0,255], exp field >= 1
    return __uint_as_float(((b & 0x80u) << 24) | (((b & 0x7Fu) << 20) + 0x3C000000u));
}

// ---------------------------------------------------------------------------
// Heterogeneous dispatch: blocks [0, 3*NT) bin edges (reg-cached single-read);
// blocks [3*NT, 3*NT+GEMM_BLKS) run the MFMA GEMM. h stored as e4m3 (3.2 MB).
__global__ __launch_bounds__(512, 8) void k_gb(
    const float* __restrict__ feat, const float* __restrict__ Wg,
    const float* __restrict__ bg, const float* __restrict__ as_,
    const float* __restrict__ ad_, const float* __restrict__ Wp,
    const float* __restrict__ bp,
    unsigned char* __restrict__ h8, unsigned short* __restrict__ hp16,
    float* __restrict__ ssrc, float* __restrict__ sdst,
    const int* __restrict__ lu, const int* __restrict__ ld,
    const int* __restrict__ pi, const float* __restrict__ pv,
    int* __restrict__ cnt,
    unsigned* __restrict__ bglu, unsigned* __restrict__ bgld,
    unsigned* __restrict__ bgpc, unsigned short* __restrict__ bgpv)
{
    __shared__ union {
        struct { unsigned short wg[4096]; unsigned short wp[4096]; } g;
        struct { int hist[NBK]; int loff[NBK]; int gbase[NBK];
                 int part[512]; unsigned stage[TSZ]; } b;
    } sm;
    int t = threadIdx.x;

    if (blockIdx.x >= 3 * NT) {
        // ----------------- GEMM part -----------------
        int gbid = blockIdx.x - 3 * NT;
        for (int i = t; i < 4096; i += 512) {
            int k = i >> 6, o = i & 63;            // W[k][o] -> WT[o][k]
            sm.g.wg[o * 64 + k] = f2bf(Wg[i]);
            sm.g.wp[o * 64 + k] = f2bf(Wp[i]);
        }
        __syncthreads();
        int lane = t & 63, w = t >> 6;
        int tile = gbid * 8 + w;
        if (tile >= NTILE) return;
        int n0 = tile * 16;
        int m = lane & 15, g = lane >> 4;
        const float* frow = feat + (size_t)(n0 + m) * 64 + g * 8;
        float4 fa = *reinterpret_cast<const float4*>(frow);
        float4 fb = *reinterpret_cast<const float4*>(frow + 4);
        float4 fc = *reinterpret_cast<const float4*>(frow + 32);
        float4 fd = *reinterpret_cast<const float4*>(frow + 36);
        short8 a0, a1;
        a0[0]=(short)f2bf(fa.x); a0[1]=(short)f2bf(fa.y); a0[2]=(short)f2bf(fa.z); a0[3]=(short)f2bf(fa.w);
        a0[4]=(short)f2bf(fb.x); a0[5]=(short)f2bf(fb.y); a0[6]=(short)f2bf(fb.z); a0[7]=(short)f2bf(fb.w);
        a1[0]=(short)f2bf(fc.x); a1[1]=(short)f2bf(fc.y); a1[2]=(short)f2bf(fc.z); a1[3]=(short)f2bf(fc.w);
        a1[4]=(short)f2bf(fd.x); a1[5]=(short)f2bf(fd.y); a1[6]=(short)f2bf(fd.z); a1[7]=(short)f2bf(fd.w);
        float ps[4] = {0.f,0.f,0.f,0.f}, pd[4] = {0.f,0.f,0.f,0.f};
#pragma unroll
        for (int tc = 0; tc < 4; ++tc) {
            const unsigned short* bgp = &sm.g.wg[(16 * tc + m) * 64 + g * 8];
            short8 b0 = *reinterpret_cast<const short8*>(bgp);
            short8 b1 = *reinterpret_cast<const short8*>(bgp + 32);
            f32x4 c = {0.f, 0.f, 0.f, 0.f};
            c = __builtin_amdgcn_mfma_f32_16x16x32_bf16(a0, b0, c, 0, 0, 0);
            c = __builtin_amdgcn_mfma_f32_16x16x32_bf16(a1, b1, c, 0, 0, 0);
            const unsigned short* bpp = &sm.g.wp[(16 * tc + m) * 64 + g * 8];
            short8 d0 = *reinterpret_cast<const short8*>(bpp);
            short8 d1 = *reinterpret_cast<const short8*>(bpp + 32);
            f32x4 e = {0.f, 0.f, 0.f, 0.f};
            e = __builtin_amdgcn_mfma_f32_16x16x32_bf16(a0, d0, e, 0, 0, 0);
            e = __builtin_amdgcn_mfma_f32_16x16x32_bf16(a1, d1, e, 0, 0, 0);
            int col = 16 * tc + m;
            float bgv = bg[col], bpv = bp[col];
            float asv = as_[col], adv = ad_[col];
#pragma unroll
            for (int r = 0; r < 4; ++r) {
                float hv = c[r] + bgv;
                int row = n0 + g * 4 + r;
                h8[(size_t)row * 64 + col] = (unsigned char)f2e4m3(hv);
                ps[r] = fmaf(hv, asv, ps[r]);
                pd[r] = fmaf(hv, adv, pd[r]);
                float pv2 = e[r] + bpv;
                hp16[(size_t)row * 64 + col] = f2bf(pv2);
            }
        }
#pragma unroll
        for (int o = 1; o < 16; o <<= 1) {
#pragma unroll
            for (int r = 0; r < 4; ++r) {
                ps[r] += __shfl_xor(ps[r], o, 64);
                pd[r] += __shfl_xor(pd[r], o, 64);
            }
        }
        if (m == 0) {
#pragma unroll
            for (int r = 0; r < 4; ++r) {
                ssrc[n0 + g * 4 + r] = ps[r];
                sdst[n0 + g * 4 + r] = pd[r];
            }
        }
        return;
    }

    // ----------------- BIN part (reg-cached single global read) -----------
    int task = blockIdx.x;
    int list = task / NT, tile = task - list * NT;
    int e0 = tile * TSZ, e1 = min(e0 + TSZ, EE), sz = e1 - e0;
    const int* srcp; const int* dstp;
    if (list == 0)      { srcp = lu;      dstp = lu + EE; }
    else if (list == 1) { srcp = ld;      dstp = ld + EE; }
    else                { srcp = pi + EE; dstp = pi; }
    for (int i = t; i < NBK; i += 512) sm.b.hist[i] = 0;
    __syncthreads();
    unsigned pay[16];
    int nmy = 0;
    if (list == 2) {
        for (int k = 0; k < 16; ++k) {
            int i = t + 512 * k;
            if (i < sz) {
                int d = dstp[e0 + i];
                pay[k] = (unsigned)i | ((unsigned)d << 16);
                atomicAdd(&sm.b.hist[d >> BSH], 1);
                nmy = k + 1;
            }
        }
    } else {
        for (int k = 0; k < 16; ++k) {
            int i = t + 512 * k;
            if (i < sz) {
                int d = dstp[e0 + i];
                pay[k] = (unsigned)srcp[e0 + i] | ((unsigned)d << 16);
                atomicAdd(&sm.b.hist[d >> BSH], 1);
                nmy = k + 1;
            }
        }
    }
    __syncthreads();
    {
        int s = (t < NBK) ? sm.b.hist[t] : 0;
        sm.b.part[t] = s;
        __syncthreads();
        for (int d = 1; d < 512; d <<= 1) {
            int v = 0;
            if (t >= d) v = sm.b.part[t - d];
            __syncthreads();
            if (t >= d) sm.b.part[t] += v;
            __syncthreads();
        }
        if (t < NBK) sm.b.loff[t] = sm.b.part[t] - s;    // exclusive
    }
    __syncthreads();
    for (int i = t; i < NBK; i += 512) {
        int c = sm.b.hist[i];
        if (c) {
            int pos = atomicAdd(&cnt[(list * NBK + i) * 16], c);
            sm.b.gbase[i] = i * CAPB + pos;
        }
        sm.b.hist[i] = sm.b.loff[i];
    }
    __syncthreads();
    for (int k = 0; k < nmy; ++k) {
        int b = (int)(pay[k] >> (16 + BSH));
        int r = atomicAdd(&sm.b.hist[b], 1);
        sm.b.stage[r] = pay[k];
    }
    __syncthreads();
    if (list == 2) {
        for (int i = t; i < sz; i += 512) {
            unsigned v = sm.b.stage[i];
            int b = (int)(v >> (16 + BSH));
            int li = (int)(v & 0xFFFFu);
            int addr = sm.b.gbase[b] + (i - sm.b.loff[b]);
            bgpc[addr] = (unsigned)srcp[e0 + li] | (v & 0xFFFF0000u);
            bgpv[addr] = f2bf(pv[e0 + li]);
        }
    } else {
        unsigned* arr = list ? bgld : bglu;
        for (int i = t; i < sz; i += 512) {
            unsigned v = sm.b.stage[i];
            int b = (int)(v >> (16 + BSH));
            arr[sm.b.gbase[b] + (i - sm.b.loff[b])] = v;
        }
    }
}

// ---------------------------------------------------------------------------
// per-(list,bucket): refine bucket region to per-node CSR IN PLACE; emits
// poff = (region_start<<8)|deg. GAT payload rewritten to
// src | bf16(exp(leaky(ssrc+sdst)))<<16 ; p payload to col | bf16(val)<<16.
__global__ __launch_bounds__(512) void k_b2c(
    const int* __restrict__ cnt,
    unsigned* __restrict__ bglu, unsigned* __restrict__ bgld,
    unsigned* __restrict__ bgpc, const unsigned short* __restrict__ bgpv,
    const float* __restrict__ ssrc, const float* __restrict__ sdst,
    int* __restrict__ poff)
{
    __shared__ int ecnt[BSZ];
    __shared__ int scn[BSZ];
    __shared__ unsigned buf[CAPB];
    __shared__ unsigned short bufv[CAPB];
    int bid  = blockIdx.x;
    int list = bid / NBK, b = bid - list * NBK;
    int size = min(cnt[(list * NBK + b) * 16], CAPB);
    int base = b * CAPB;
    int t = threadIdx.x;
    if (t < BSZ) ecnt[t] = 0;
    __syncthreads();
    unsigned* arr = (list == 0) ? bglu : (list == 1) ? bgld : bgpc;
    for (int i = t; i < size; i += 512) {
        unsigned v = arr[base + i];
        buf[i] = v;
        if (list == 2) bufv[i] = bgpv[base + i];
        atomicAdd(&ecnt[(v >> 16) & (BSZ - 1)], 1);
    }
    __syncthreads();
    if (t < BSZ) scn[t] = ecnt[t];
    __syncthreads();
    for (int d = 1; d < BSZ; d <<= 1) {
        int add = 0;
        if (t < BSZ && t >= d) add = scn[t - d];
        __syncthreads();
        if (t < BSZ && t >= d) scn[t] += add;
        __syncthreads();
    }
    int n0 = b << BSH;
    if (t < BSZ) {
        int deg  = ecnt[t];
        int excl = scn[t] - deg;
        if (n0 + t < NN)
            poff[list * NN + n0 + t] = ((base + excl) << 8) | deg;
    }
    __syncthreads();
    if (t < BSZ) ecnt[t] = scn[t] - ecnt[t];     // cursors
    __syncthreads();
    if (list == 2) {
        for (int i = t; i < size; i += 512) {
            unsigned v = buf[i];
            int pos = atomicAdd(&ecnt[(v >> 16) & (BSZ - 1)], 1);
            arr[base + pos] = (v & 0xFFFFu) | ((unsigned)bufv[i] << 16);
        }
    } else {
        for (int i = t; i < size; i += 512) {
            unsigned v = buf[i];
            int src = (int)(v & 0xFFFFu);
            int dst = (int)(v >> 16);
            float ex = __expf(leaky(ssrc[src] + sdst[dst]));
            int pos = atomicAdd(&ecnt[(v >> 16) & (BSZ - 1)], 1);
            arr[base + pos] = (unsigned)src | ((unsigned)f2bf(ex) << 16);
        }
    }
}

// ---------------------------------------------------------------------------
// GAT gather: TWO nodes per wave (32-lane halves), payload src|bf16(w)<<16.
// h table is e4m3: 64 B rows, 16 lanes x uint (4 ch/lane), branch-free decode.
__global__ __launch_bounds__(256) void k_ggat(
    const int* __restrict__ poff,
    const unsigned* __restrict__ glu, const unsigned* __restrict__ gld,
    const unsigned char* __restrict__ h8, float* __restrict__ out)
{
    int lane = threadIdx.x & 63;
    int half = lane >> 5;            // node within pair
    int hl   = lane & 31;            // lane within half
    int rg   = (lane >> 4) & 1;      // row-group within half
    int cid  = lane & 15;            // channel-quad id
    int wid  = blockIdx.x * (blockDim.x >> 6) + (threadIdx.x >> 6);
    int nw   = gridDim.x * (blockDim.x >> 6);
    for (int p = wid; p < NN / 2; p += nw) {
        int n = 2 * p + half;
        float t0 = 0.f, t1 = 0.f, t2 = 0.f, t3 = 0.f;
        for (int list = 0; list < 2; ++list) {
            const unsigned* arr = list ? gld : glu;
            int word = poff[list * NN + n];
            int b = word >> 8, deg = word & 255;
            int e = b + deg;
            int dW = max(deg, __shfl_xor(deg, 32, 64));   // wave-uniform
            if (dW <= 0) continue;
            float a0 = 0.f, a1 = 0.f, a2 = 0.f, a3 = 0.f;
            float b0 = 0.f, b1 = 0.f, b2 = 0.f, b3 = 0.f;
            float c0 = 0.f, c1 = 0.f, c2 = 0.f, c3 = 0.f;
            float d0 = 0.f, d1 = 0.f, d2 = 0.f, d3 = 0.f;
            float den = 0.f;
            for (int cb = 0; cb < dW; cb += 32) {
                int j  = b + cb + hl;
                int jc = max(min(j, e - 1), 0);
                unsigned cv = arr[jc];
                if (j >= e) cv &= 0xFFFFu;       // zero weight on tail
                den += __uint_as_float(cv & 0xFFFF0000u);
                int c32 = min(32, dW - cb);
                int sb0 = (half << 5) + rg;
                for (int k = 0; k < c32; k += 8) {
                    int sb = sb0 + k;
                    unsigned q0 = (unsigned)__shfl((int)cv, sb,     64);
                    unsigned q1 = (unsigned)__shfl((int)cv, sb + 2, 64);
                    unsigned q2 = (unsigned)__shfl((int)cv, sb + 4, 64);
                    unsigned q3 = (unsigned)__shfl((int)cv, sb + 6, 64);
                    int   s0 = (int)(q0 & 0xFFFFu), s1 = (int)(q1 & 0xFFFFu);
                    int   s2 = (int)(q2 & 0xFFFFu), s3 = (int)(q3 & 0xFFFFu);
                    float w0 = __uint_as_float(q0 & 0xFFFF0000u);
                    float w1 = __uint_as_float(q1 & 0xFFFF0000u);
                    float w2 = __uint_as_float(q2 & 0xFFFF0000u);
                    float w3 = __uint_as_float(q3 & 0xFFFF0000u);
                    unsigned r0 = *reinterpret_cast<const unsigned*>(h8 + (size_t)s0 * 64 + cid * 4);
                    unsigned r1 = *reinterpret_cast<const unsigned*>(h8 + (size_t)s1 * 64 + cid * 4);
                    unsigned r2 = *reinterpret_cast<const unsigned*>(h8 + (size_t)s2 * 64 + cid * 4);
                    unsigned r3 = *reinterpret_cast<const unsigned*>(h8 + (size_t)s3 * 64 + cid * 4);
                    a0 = fmaf(w0, e4m3f(r0 & 0xFFu), a0);
                    a1 = fmaf(w0, e4m3f((r0 >> 8) & 0xFFu), a1);
                    a2 = fmaf(w0, e4m3f((r0 >> 16) & 0xFFu), a2);
                    a3 = fmaf(w0, e4m3f(r0 >> 24), a3);
                    b0 = fmaf(w1, e4m3f(r1 & 0xFFu), b0);
                    b1 = fmaf(w1, e4m3f((r1 >> 8) & 0xFFu), b1);
                    b2 = fmaf(w1, e4m3f((r1 >> 16) & 0xFFu), b2);
                    b3 = fmaf(w1, e4m3f(r1 >> 24), b3);
                    c0 = fmaf(w2, e4m3f(r2 & 0xFFu), c0);
                    c1 = fmaf(w2, e4m3f((r2 >> 8) & 0xFFu), c1);
                    c2 = fmaf(w2, e4m3f((r2 >> 16) & 0xFFu), c2);
                    c3 = fmaf(w2, e4m3f(r2 >> 24), c3);
                    d0 = fmaf(w3, e4m3f(r3 & 0xFFu), d0);
                    d1 = fmaf(w3, e4m3f((r3 >> 8) & 0xFFu), d1);
                    d2 = fmaf(w3, e4m3f((r3 >> 16) & 0xFFu), d2);
                    d3 = fmaf(w3, e4m3f(r3 >> 24), d3);
                }
            }
#pragma unroll
            for (int o = 1; o <= 16; o <<= 1) den += __shfl_xor(den, o, 64);
            float inv = 1.f / (den + 1e-16f);
            float u0 = (a0 + b0) + (c0 + d0);
            float u1 = (a1 + b1) + (c1 + d1);
            float u2 = (a2 + b2) + (c2 + d2);
            float u3 = (a3 + b3) + (c3 + d3);
            u0 += __shfl_xor(u0, 16, 64);
            u1 += __shfl_xor(u1, 16, 64);
            u2 += __shfl_xor(u2, 16, 64);
            u3 += __shfl_xor(u3, 16, 64);
            t0 = fmaf(u0, inv, t0); t1 = fmaf(u1, inv, t1);
            t2 = fmaf(u2, inv, t2); t3 = fmaf(u3, inv, t3);
        }
        if (hl < 16) {
            float4 o4; o4.x = t0; o4.y = t1; o4.z = t2; o4.w = t3;
            *reinterpret_cast<float4*>(out + (size_t)n * 64 + cid * 4) = o4;
        }
    }
}

// ---------------------------------------------------------------------------
// p-list SpMM gather, two nodes per wave; payload col|bf16(val)<<16 in bgpc.
__global__ __launch_bounds__(256) void k_gp(
    const int* __restrict__ poff, const unsigned* __restrict__ cv32,
    const unsigned short* __restrict__ hp16, float* __restrict__ out)
{
    int lane = threadIdx.x & 63;
    int half = lane >> 5;
    int hl   = lane & 31;
    int rg   = (lane >> 4) & 1;
    int cid  = lane & 15;
    int wid  = blockIdx.x * (blockDim.x >> 6) + (threadIdx.x >> 6);
    int nw   = gridDim.x * (blockDim.x >> 6);
    for (int p = wid; p < NN / 2; p += nw) {
        int n = 2 * p + half;
        int word = poff[2 * NN + n];
        int b = word >> 8, deg = word & 255;
        int e = b + deg;
        int dW = max(deg, __shfl_xor(deg, 32, 64));
        f32x2 A0={0.f,0.f}, A1={0.f,0.f}, B0={0.f,0.f}, B1={0.f,0.f};
        f32x2 C0={0.f,0.f}, C1={0.f,0.f}, D0={0.f,0.f}, D1={0.f,0.f};
        for (int cb = 0; cb < dW; cb += 32) {
            int j  = b + cb + hl;
            int jc = max(min(j, e - 1), 0);
            unsigned cv = cv32[jc];
            if (j >= e) cv &= 0xFFFFu;
            int c32 = min(32, dW - cb);
            int sb0 = (half << 5) + rg;
            for (int k = 0; k < c32; k += 8) {
                int sb = sb0 + k;
                unsigned q0 = (unsigned)__shfl((int)cv, sb,     64);
                unsigned q1 = (unsigned)__shfl((int)cv, sb + 2, 64);
                unsigned q2 = (unsigned)__shfl((int)cv, sb + 4, 64);
                unsigned q3 = (unsigned)__shfl((int)cv, sb + 6, 64);
                int   s0 = (int)(q0 & 0xFFFFu), s1 = (int)(q1 & 0xFFFFu);
                int   s2 = (int)(q2 & 0xFFFFu), s3 = (int)(q3 & 0xFFFFu);
                float w0 = __uint_as_float(q0 & 0xFFFF0000u);
                float w1 = __uint_as_float(q1 & 0xFFFF0000u);
                float w2 = __uint_as_float(q2 & 0xFFFF0000u);
                float w3 = __uint_as_float(q3 & 0xFFFF0000u);
                uint2 r0 = *reinterpret_cast<const uint2*>(hp16 + (size_t)s0 * 64 + cid * 4);
                uint2 r1 = *reinterpret_cast<const uint2*>(hp16 + (size_t)s1 * 64 + cid * 4);
                uint2 r2 = *reinterpret_cast<const uint2*>(hp16 + (size_t)s2 * 64 + cid * 4);
                uint2 r3 = *reinterpret_cast<const uint2*>(hp16 + (size_t)s3 * 64 + cid * 4);
                f32x2 h;
                h.x = __uint_as_float(r0.x << 16); h.y = __uint_as_float(r0.x & 0xFFFF0000u);
                A0 += h * w0;
                h.x = __uint_as_float(r0.y << 16); h.y = __uint_as_float(r0.y & 0xFFFF0000u);
                A1 += h * w0;
                h.x = __uint_as_float(r1.x << 16); h.y = __uint_as_float(r1.x & 0xFFFF0000u);
                B0 += h * w1;
                h.x = __uint_as_float(r1.y << 16); h.y = __uint_as_float(r1.y & 0xFFFF0000u);
                B1 += h * w1;
                h.x = __uint_as_float(r2.x << 16); h.y = __uint_as_float(r2.x & 0xFFFF0000u);
                C0 += h * w2;
                h.x = __uint_as_float(r2.y << 16); h.y = __uint_as_float(r2.y & 0xFFFF0000u);
                C1 += h * w2;
                h.x = __uint_as_float(r3.x << 16); h.y = __uint_as_float(r3.x & 0xFFFF0000u);
                D0 += h * w3;
                h.x = __uint_as_float(r3.y << 16); h.y = __uint_as_float(r3.y & 0xFFFF0000u);
                D1 += h * w3;
            }
        }
        f32x2 U0 = (A0 + B0) + (C0 + D0);
        f32x2 U1 = (A1 + B1) + (C1 + D1);
        float u0 = U0.x, u1 = U0.y, u2 = U1.x, u3 = U1.y;
        u0 += __shfl_xor(u0, 16, 64);
        u1 += __shfl_xor(u1, 16, 64);
        u2 += __shfl_xor(u2, 16, 64);
        u3 += __shfl_xor(u3, 16, 64);
        if (hl < 16) {
            float4 o4 = *reinterpret_cast<float4*>(out + (size_t)n * 64 + cid * 4);
            o4.x += u0; o4.y += u1; o4.z += u2; o4.w += u3;
            *reinterpret_cast<float4*>(out + (size_t)n * 64 + cid * 4) = o4;
        }
    }
}

// ---------------------------------------------------------------------------
extern "C" void kernel_launch(void* const* d_in, const int* in_sizes, int n_in,
                              void* d_out, int out_size, void* d_ws, size_t ws_size,
                              hipStream_t stream)
{
    const float* feat = (const float*)d_in[0];
    const float* Wg   = (const float*)d_in[1];
    const float* bg   = (const float*)d_in[2];
    const float* as_  = (const float*)d_in[3];
    const float* ad_  = (const float*)d_in[4];
    const float* Wp   = (const float*)d_in[5];
    const float* bp   = (const float*)d_in[6];
    const float* pv   = (const float*)d_in[7];
    const int*   lu   = (const int*)d_in[8];
    const int*   ld   = (const int*)d_in[9];
    const int*   pi   = (const int*)d_in[10];
    float* out = (float*)d_out;

    unsigned short* hp16 = (unsigned short*)d_ws;        // NN*64 ushort
    unsigned char*  h8   = (unsigned char*)(hp16 + (size_t)NN * 64); // NN*64 bytes
    float* fbase = (float*)(h8 + (size_t)NN * 64);
    float* ssrc  = fbase;                                // NN
    float* sdst  = ssrc + NN;                            // NN
    int*   poff  = (int*)(sdst + NN);                    // 3*NN packed (start<<8|deg)
    int*   cnt   = poff + 3 * NN;                        // 3*NBK*16 (64B-padded)
    unsigned* bglu = (unsigned*)(cnt + 3 * NBK * 16);    // NBK*CAPB
    unsigned* bgld = bglu + (size_t)NBK * CAPB;          // NBK*CAPB
    unsigned* bgpc = bgld + (size_t)NBK * CAPB;          // NBK*CAPB
    unsigned short* bgpv = (unsigned short*)(bgpc + (size_t)NBK * CAPB); // NBK*CAPB us

    hipMemsetAsync(cnt, 0, (size_t)(3 * NBK * 16) * sizeof(int), stream);
    hipLaunchKernelGGL(k_gb, dim3(3 * NT + GEMM_BLKS), dim3(512), 0, stream,
                       feat, Wg, bg, as_, ad_, Wp, bp, h8, hp16, ssrc, sdst,
                       lu, ld, pi, pv, cnt, bglu, bgld, bgpc, bgpv);
    hipLaunchKernelGGL(k_b2c, dim3(3 * NBK), dim3(512), 0, stream,
                       cnt, bglu, bgld, bgpc, bgpv, ssrc, sdst, poff);
    hipLaunchKernelGGL(k_ggat, dim3(2048), dim3(256), 0, stream,
                       poff, bglu, bgld, h8, out);
    hipLaunchKernelGGL(k_gp, dim3(2048), dim3(256), 0, stream,
                       poff, bgpc, hp16, out);
}

// Round 22
// 146.443 us; speedup vs baseline: 1.2462x; 1.2462x over previous
//
#include <hip/hip_runtime.h>
#include <cfloat>

#define NN 50000
#define EE 1600000
#define NEG 0.2f
#define BSH 7
#define BSZ 128                       // nodes per bucket
#define NBK ((NN + BSZ - 1) / BSZ)    // 391
#define CAPB 4608                     // fixed bucket capacity (mean 4096 + 8 sigma)
#define TSZ 8192                      // k_bin tile size (edges)
#define NT  ((EE + TSZ - 1) / TSZ)    // 196 tiles per list
#define NTILE (NN / 16)               // 3125 gemm tiles
#define GEMM_BLKS ((NTILE + 7) / 8)   // 391 (8 tiles per 512-thr block)

typedef __attribute__((ext_vector_type(8))) short short8;
typedef __attribute__((ext_vector_type(4))) float f32x4;
typedef __attribute__((ext_vector_type(2))) float f32x2;

__device__ inline float leaky(float v) { return fmaxf(v, NEG * v); }

__device__ inline unsigned short f2bf(float f) {
    unsigned u = __float_as_uint(f);
    u += 0x7FFFu + ((u >> 16) & 1u);          // round-to-nearest-even
    return (unsigned short)(u >> 16);
}
__device__ inline float bf2f(unsigned short s) {
    return __uint_as_float(((unsigned)s) << 16);
}

// ---------------------------------------------------------------------------
// Heterogeneous dispatch: blocks [0, 3*NT) bin edges (reg-cached single-read);
// blocks [3*NT, 3*NT+GEMM_BLKS) run the MFMA GEMM.
__global__ __launch_bounds__(512, 8) void k_gb(
    const float* __restrict__ feat, const float* __restrict__ Wg,
    const float* __restrict__ bg, const float* __restrict__ as_,
    const float* __restrict__ ad_, const float* __restrict__ Wp,
    const float* __restrict__ bp,
    unsigned short* __restrict__ h16, unsigned short* __restrict__ hp16,
    float* __restrict__ ssrc, float* __restrict__ sdst,
    const int* __restrict__ lu, const int* __restrict__ ld,
    const int* __restrict__ pi, const float* __restrict__ pv,
    int* __restrict__ cnt,
    unsigned* __restrict__ bglu, unsigned* __restrict__ bgld,
    unsigned* __restrict__ bgpc, unsigned short* __restrict__ bgpv)
{
    __shared__ union {
        struct { unsigned short wg[4096]; unsigned short wp[4096]; } g;
        struct { int hist[NBK]; int loff[NBK]; int gbase[NBK];
                 int part[512]; unsigned stage[TSZ]; } b;
    } sm;
    int t = threadIdx.x;

    if (blockIdx.x >= 3 * NT) {
        // ----------------- GEMM part -----------------
        int gbid = blockIdx.x - 3 * NT;
        for (int i = t; i < 4096; i += 512) {
            int k = i >> 6, o = i & 63;            // W[k][o] -> WT[o][k]
            sm.g.wg[o * 64 + k] = f2bf(Wg[i]);
            sm.g.wp[o * 64 + k] = f2bf(Wp[i]);
        }
        __syncthreads();
        int lane = t & 63, w = t >> 6;
        int tile = gbid * 8 + w;
        if (tile >= NTILE) return;
        int n0 = tile * 16;
        int m = lane & 15, g = lane >> 4;
        const float* frow = feat + (size_t)(n0 + m) * 64 + g * 8;
        float4 fa = *reinterpret_cast<const float4*>(frow);
        float4 fb = *reinterpret_cast<const float4*>(frow + 4);
        float4 fc = *reinterpret_cast<const float4*>(frow + 32);
        float4 fd = *reinterpret_cast<const float4*>(frow + 36);
        short8 a0, a1;
        a0[0]=(short)f2bf(fa.x); a0[1]=(short)f2bf(fa.y); a0[2]=(short)f2bf(fa.z); a0[3]=(short)f2bf(fa.w);
        a0[4]=(short)f2bf(fb.x); a0[5]=(short)f2bf(fb.y); a0[6]=(short)f2bf(fb.z); a0[7]=(short)f2bf(fb.w);
        a1[0]=(short)f2bf(fc.x); a1[1]=(short)f2bf(fc.y); a1[2]=(short)f2bf(fc.z); a1[3]=(short)f2bf(fc.w);
        a1[4]=(short)f2bf(fd.x); a1[5]=(short)f2bf(fd.y); a1[6]=(short)f2bf(fd.z); a1[7]=(short)f2bf(fd.w);
        float ps[4] = {0.f,0.f,0.f,0.f}, pd[4] = {0.f,0.f,0.f,0.f};
#pragma unroll
        for (int tc = 0; tc < 4; ++tc) {
            const unsigned short* bgp = &sm.g.wg[(16 * tc + m) * 64 + g * 8];
            short8 b0 = *reinterpret_cast<const short8*>(bgp);
            short8 b1 = *reinterpret_cast<const short8*>(bgp + 32);
            f32x4 c = {0.f, 0.f, 0.f, 0.f};
            c = __builtin_amdgcn_mfma_f32_16x16x32_bf16(a0, b0, c, 0, 0, 0);
            c = __builtin_amdgcn_mfma_f32_16x16x32_bf16(a1, b1, c, 0, 0, 0);
            const unsigned short* bpp = &sm.g.wp[(16 * tc + m) * 64 + g * 8];
            short8 d0 = *reinterpret_cast<const short8*>(bpp);
            short8 d1 = *reinterpret_cast<const short8*>(bpp + 32);
            f32x4 e = {0.f, 0.f, 0.f, 0.f};
            e = __builtin_amdgcn_mfma_f32_16x16x32_bf16(a0, d0, e, 0, 0, 0);
            e = __builtin_amdgcn_mfma_f32_16x16x32_bf16(a1, d1, e, 0, 0, 0);
            int col = 16 * tc + m;
            float bgv = bg[col], bpv = bp[col];
            float asv = as_[col], adv = ad_[col];
#pragma unroll
            for (int r = 0; r < 4; ++r) {
                float hv = c[r] + bgv;
                int row = n0 + g * 4 + r;
                h16[(size_t)row * 64 + col] = f2bf(hv);
                ps[r] = fmaf(hv, asv, ps[r]);
                pd[r] = fmaf(hv, adv, pd[r]);
                float pv2 = e[r] + bpv;
                hp16[(size_t)row * 64 + col] = f2bf(pv2);
            }
        }
#pragma unroll
        for (int o = 1; o < 16; o <<= 1) {
#pragma unroll
            for (int r = 0; r < 4; ++r) {
                ps[r] += __shfl_xor(ps[r], o, 64);
                pd[r] += __shfl_xor(pd[r], o, 64);
            }
        }
        if (m == 0) {
#pragma unroll
            for (int r = 0; r < 4; ++r) {
                ssrc[n0 + g * 4 + r] = ps[r];
                sdst[n0 + g * 4 + r] = pd[r];
            }
        }
        return;
    }

    // ----------------- BIN part (reg-cached single global read) -----------
    int task = blockIdx.x;
    int list = task / NT, tile = task - list * NT;
    int e0 = tile * TSZ, e1 = min(e0 + TSZ, EE), sz = e1 - e0;
    const int* srcp; const int* dstp;
    if (list == 0)      { srcp = lu;      dstp = lu + EE; }
    else if (list == 1) { srcp = ld;      dstp = ld + EE; }
    else                { srcp = pi + EE; dstp = pi; }
    for (int i = t; i < NBK; i += 512) sm.b.hist[i] = 0;
    __syncthreads();
    // phase 1: load edges once into registers, pack, histogram.
    unsigned pay[16];
    int nmy = 0;
    if (list == 2) {
        // payload = tile_local_idx | dst<<16 (col/val re-read L2-hot later)
        for (int k = 0; k < 16; ++k) {
            int i = t + 512 * k;
            if (i < sz) {
                int d = dstp[e0 + i];
                pay[k] = (unsigned)i | ((unsigned)d << 16);
                atomicAdd(&sm.b.hist[d >> BSH], 1);
                nmy = k + 1;
            }
        }
    } else {
        for (int k = 0; k < 16; ++k) {
            int i = t + 512 * k;
            if (i < sz) {
                int d = dstp[e0 + i];
                pay[k] = (unsigned)srcp[e0 + i] | ((unsigned)d << 16);
                atomicAdd(&sm.b.hist[d >> BSH], 1);
                nmy = k + 1;
            }
        }
    }
    __syncthreads();
    {
        int s = (t < NBK) ? sm.b.hist[t] : 0;
        sm.b.part[t] = s;
        __syncthreads();
        for (int d = 1; d < 512; d <<= 1) {
            int v = 0;
            if (t >= d) v = sm.b.part[t - d];
            __syncthreads();
            if (t >= d) sm.b.part[t] += v;
            __syncthreads();
        }
        if (t < NBK) sm.b.loff[t] = sm.b.part[t] - s;    // exclusive
    }
    __syncthreads();
    for (int i = t; i < NBK; i += 512) {
        int c = sm.b.hist[i];
        if (c) {
            int pos = atomicAdd(&cnt[(list * NBK + i) * 16], c);
            sm.b.gbase[i] = i * CAPB + pos;
        }
        sm.b.hist[i] = sm.b.loff[i];
    }
    __syncthreads();
    // phase 2: stage from registers (no global re-read)
    for (int k = 0; k < nmy; ++k) {
        int b = (int)(pay[k] >> (16 + BSH));
        int r = atomicAdd(&sm.b.hist[b], 1);
        sm.b.stage[r] = pay[k];
    }
    __syncthreads();
    // phase 3: coalesced write-out per bucket run
    if (list == 2) {
        for (int i = t; i < sz; i += 512) {
            unsigned v = sm.b.stage[i];
            int b = (int)(v >> (16 + BSH));
            int li = (int)(v & 0xFFFFu);
            int addr = sm.b.gbase[b] + (i - sm.b.loff[b]);
            bgpc[addr] = (unsigned)srcp[e0 + li] | (v & 0xFFFF0000u);
            bgpv[addr] = f2bf(pv[e0 + li]);
        }
    } else {
        unsigned* arr = list ? bgld : bglu;
        for (int i = t; i < sz; i += 512) {
            unsigned v = sm.b.stage[i];
            int b = (int)(v >> (16 + BSH));
            arr[sm.b.gbase[b] + (i - sm.b.loff[b])] = v;
        }
    }
}

// ---------------------------------------------------------------------------
// per-(list,bucket): refine bucket region to per-node CSR IN PLACE; emits
// poff = (region_start<<8)|deg. GAT payload rewritten to
// src | bf16(exp(leaky(ssrc+sdst)))<<16 ; p payload to col | bf16(val)<<16.
__global__ __launch_bounds__(512) void k_b2c(
    const int* __restrict__ cnt,
    unsigned* __restrict__ bglu, unsigned* __restrict__ bgld,
    unsigned* __restrict__ bgpc, const unsigned short* __restrict__ bgpv,
    const float* __restrict__ ssrc, const float* __restrict__ sdst,
    int* __restrict__ poff)
{
    __shared__ int ecnt[BSZ];
    __shared__ int scn[BSZ];
    __shared__ unsigned buf[CAPB];
    __shared__ unsigned short bufv[CAPB];
    int bid  = blockIdx.x;
    int list = bid / NBK, b = bid - list * NBK;
    int size = min(cnt[(list * NBK + b) * 16], CAPB);
    int base = b * CAPB;
    int t = threadIdx.x;
    if (t < BSZ) ecnt[t] = 0;
    __syncthreads();
    unsigned* arr = (list == 0) ? bglu : (list == 1) ? bgld : bgpc;
    for (int i = t; i < size; i += 512) {
        unsigned v = arr[base + i];
        buf[i] = v;
        if (list == 2) bufv[i] = bgpv[base + i];
        atomicAdd(&ecnt[(v >> 16) & (BSZ - 1)], 1);
    }
    __syncthreads();
    if (t < BSZ) scn[t] = ecnt[t];
    __syncthreads();
    for (int d = 1; d < BSZ; d <<= 1) {
        int add = 0;
        if (t < BSZ && t >= d) add = scn[t - d];
        __syncthreads();
        if (t < BSZ && t >= d) scn[t] += add;
        __syncthreads();
    }
    int n0 = b << BSH;
    if (t < BSZ) {
        int deg  = ecnt[t];
        int excl = scn[t] - deg;
        if (n0 + t < NN)
            poff[list * NN + n0 + t] = ((base + excl) << 8) | deg;
    }
    __syncthreads();
    if (t < BSZ) ecnt[t] = scn[t] - ecnt[t];     // cursors
    __syncthreads();
    if (list == 2) {
        for (int i = t; i < size; i += 512) {
            unsigned v = buf[i];
            int pos = atomicAdd(&ecnt[(v >> 16) & (BSZ - 1)], 1);
            arr[base + pos] = (v & 0xFFFFu) | ((unsigned)bufv[i] << 16);
        }
    } else {
        for (int i = t; i < size; i += 512) {
            unsigned v = buf[i];
            int src = (int)(v & 0xFFFFu);
            int dst = (int)(v >> 16);
            float ex = __expf(leaky(ssrc[src] + sdst[dst]));
            int pos = atomicAdd(&ecnt[(v >> 16) & (BSZ - 1)], 1);
            arr[base + pos] = (unsigned)src | ((unsigned)f2bf(ex) << 16);
        }
    }
}

// ---------------------------------------------------------------------------
// GAT gather: TWO nodes per wave (32-lane halves), payload src|bf16(w)<<16.
__global__ __launch_bounds__(256) void k_ggat(
    const int* __restrict__ poff,
    const unsigned* __restrict__ glu, const unsigned* __restrict__ gld,
    const unsigned short* __restrict__ h16, float* __restrict__ out)
{
    int lane = threadIdx.x & 63;
    int half = lane >> 5;            // node within pair
    int hl   = lane & 31;            // lane within half
    int rg   = (lane >> 4) & 1;      // row-group within half
    int cid  = lane & 15;            // channel-quad id
    int wid  = blockIdx.x * (blockDim.x >> 6) + (threadIdx.x >> 6);
    int nw   = gridDim.x * (blockDim.x >> 6);
    for (int p = wid; p < NN / 2; p += nw) {
        int n = 2 * p + half;
        float t0 = 0.f, t1 = 0.f, t2 = 0.f, t3 = 0.f;
        for (int list = 0; list < 2; ++list) {
            const unsigned* arr = list ? gld : glu;
            int word = poff[list * NN + n];
            int b = word >> 8, deg = word & 255;
            int e = b + deg;
            int dW = max(deg, __shfl_xor(deg, 32, 64));   // wave-uniform
            if (dW <= 0) continue;
            f32x2 A0={0.f,0.f}, A1={0.f,0.f}, B0={0.f,0.f}, B1={0.f,0.f};
            f32x2 C0={0.f,0.f}, C1={0.f,0.f}, D0={0.f,0.f}, D1={0.f,0.f};
            float den = 0.f;
            for (int cb = 0; cb < dW; cb += 32) {
                int j  = b + cb + hl;
                int jc = max(min(j, e - 1), 0);
                unsigned cv = arr[jc];
                if (j >= e) cv &= 0xFFFFu;       // zero weight on tail
                den += __uint_as_float(cv & 0xFFFF0000u);
                int c32 = min(32, dW - cb);
                int sb0 = (half << 5) + rg;
                for (int k = 0; k < c32; k += 8) {
                    int sb = sb0 + k;
                    unsigned q0 = (unsigned)__shfl((int)cv, sb,     64);
                    unsigned q1 = (unsigned)__shfl((int)cv, sb + 2, 64);
                    unsigned q2 = (unsigned)__shfl((int)cv, sb + 4, 64);
                    unsigned q3 = (unsigned)__shfl((int)cv, sb + 6, 64);
                    int   s0 = (int)(q0 & 0xFFFFu), s1 = (int)(q1 & 0xFFFFu);
                    int   s2 = (int)(q2 & 0xFFFFu), s3 = (int)(q3 & 0xFFFFu);
                    float w0 = __uint_as_float(q0 & 0xFFFF0000u);
                    float w1 = __uint_as_float(q1 & 0xFFFF0000u);
                    float w2 = __uint_as_float(q2 & 0xFFFF0000u);
                    float w3 = __uint_as_float(q3 & 0xFFFF0000u);
                    uint2 r0 = *reinterpret_cast<const uint2*>(h16 + (size_t)s0 * 64 + cid * 4);
                    uint2 r1 = *reinterpret_cast<const uint2*>(h16 + (size_t)s1 * 64 + cid * 4);
                    uint2 r2 = *reinterpret_cast<const uint2*>(h16 + (size_t)s2 * 64 + cid * 4);
                    uint2 r3 = *reinterpret_cast<const uint2*>(h16 + (size_t)s3 * 64 + cid * 4);
                    f32x2 h;
                    h.x = __uint_as_float(r0.x << 16); h.y = __uint_as_float(r0.x & 0xFFFF0000u);
                    A0 += h * w0;
                    h.x = __uint_as_float(r0.y << 16); h.y = __uint_as_float(r0.y & 0xFFFF0000u);
                    A1 += h * w0;
                    h.x = __uint_as_float(r1.x << 16); h.y = __uint_as_float(r1.x & 0xFFFF0000u);
                    B0 += h * w1;
                    h.x = __uint_as_float(r1.y << 16); h.y = __uint_as_float(r1.y & 0xFFFF0000u);
                    B1 += h * w1;
                    h.x = __uint_as_float(r2.x << 16); h.y = __uint_as_float(r2.x & 0xFFFF0000u);
                    C0 += h * w2;
                    h.x = __uint_as_float(r2.y << 16); h.y = __uint_as_float(r2.y & 0xFFFF0000u);
                    C1 += h * w2;
                    h.x = __uint_as_float(r3.x << 16); h.y = __uint_as_float(r3.x & 0xFFFF0000u);
                    D0 += h * w3;
                    h.x = __uint_as_float(r3.y << 16); h.y = __uint_as_float(r3.y & 0xFFFF0000u);
                    D1 += h * w3;
                }
            }
#pragma unroll
            for (int o = 1; o <= 16; o <<= 1) den += __shfl_xor(den, o, 64);
            float inv = 1.f / (den + 1e-16f);
            f32x2 U0 = (A0 + B0) + (C0 + D0);
            f32x2 U1 = (A1 + B1) + (C1 + D1);
            float u0 = U0.x, u1 = U0.y, u2 = U1.x, u3 = U1.y;
            u0 += __shfl_xor(u0, 16, 64);
            u1 += __shfl_xor(u1, 16, 64);
            u2 += __shfl_xor(u2, 16, 64);
            u3 += __shfl_xor(u3, 16, 64);
            t0 = fmaf(u0, inv, t0); t1 = fmaf(u1, inv, t1);
            t2 = fmaf(u2, inv, t2); t3 = fmaf(u3, inv, t3);
        }
        if (hl < 16) {
            float4 o4; o4.x = t0; o4.y = t1; o4.z = t2; o4.w = t3;
            *reinterpret_cast<float4*>(out + (size_t)n * 64 + cid * 4) = o4;
        }
    }
}

// ---------------------------------------------------------------------------
// p-list SpMM gather, two nodes per wave; payload col|bf16(val)<<16 in bgpc.
__global__ __launch_bounds__(256) void k_gp(
    const int* __restrict__ poff, const unsigned* __restrict__ cv32,
    const unsigned short* __restrict__ hp16, float* __restrict__ out)
{
    int lane = threadIdx.x & 63;
    int half = lane >> 5;
    int hl   = lane & 31;
    int rg   = (lane >> 4) & 1;
    int cid  = lane & 15;
    int wid  = blockIdx.x * (blockDim.x >> 6) + (threadIdx.x >> 6);
    int nw   = gridDim.x * (blockDim.x >> 6);
    for (int p = wid; p < NN / 2; p += nw) {
        int n = 2 * p + half;
        int word = poff[2 * NN + n];
        int b = word >> 8, deg = word & 255;
        int e = b + deg;
        int dW = max(deg, __shfl_xor(deg, 32, 64));
        f32x2 A0={0.f,0.f}, A1={0.f,0.f}, B0={0.f,0.f}, B1={0.f,0.f};
        f32x2 C0={0.f,0.f}, C1={0.f,0.f}, D0={0.f,0.f}, D1={0.f,0.f};
        for (int cb = 0; cb < dW; cb += 32) {
            int j  = b + cb + hl;
            int jc = max(min(j, e - 1), 0);
            unsigned cv = cv32[jc];
            if (j >= e) cv &= 0xFFFFu;
            int c32 = min(32, dW - cb);
            int sb0 = (half << 5) + rg;
            for (int k = 0; k < c32; k += 8) {
                int sb = sb0 + k;
                unsigned q0 = (unsigned)__shfl((int)cv, sb,     64);
                unsigned q1 = (unsigned)__shfl((int)cv, sb + 2, 64);
                unsigned q2 = (unsigned)__shfl((int)cv, sb + 4, 64);
                unsigned q3 = (unsigned)__shfl((int)cv, sb + 6, 64);
                int   s0 = (int)(q0 & 0xFFFFu), s1 = (int)(q1 & 0xFFFFu);
                int   s2 = (int)(q2 & 0xFFFFu), s3 = (int)(q3 & 0xFFFFu);
                float w0 = __uint_as_float(q0 & 0xFFFF0000u);
                float w1 = __uint_as_float(q1 & 0xFFFF0000u);
                float w2 = __uint_as_float(q2 & 0xFFFF0000u);
                float w3 = __uint_as_float(q3 & 0xFFFF0000u);
                uint2 r0 = *reinterpret_cast<const uint2*>(hp16 + (size_t)s0 * 64 + cid * 4);
                uint2 r1 = *reinterpret_cast<const uint2*>(hp16 + (size_t)s1 * 64 + cid * 4);
                uint2 r2 = *reinterpret_cast<const uint2*>(hp16 + (size_t)s2 * 64 + cid * 4);
                uint2 r3 = *reinterpret_cast<const uint2*>(hp16 + (size_t)s3 * 64 + cid * 4);
                f32x2 h;
                h.x = __uint_as_float(r0.x << 16); h.y = __uint_as_float(r0.x & 0xFFFF0000u);
                A0 += h * w0;
                h.x = __uint_as_float(r0.y << 16); h.y = __uint_as_float(r0.y & 0xFFFF0000u);
                A1 += h * w0;
                h.x = __uint_as_float(r1.x << 16); h.y = __uint_as_float(r1.x & 0xFFFF0000u);
                B0 += h * w1;
                h.x = __uint_as_float(r1.y << 16); h.y = __uint_as_float(r1.y & 0xFFFF0000u);
                B1 += h * w1;
                h.x = __uint_as_float(r2.x << 16); h.y = __uint_as_float(r2.x & 0xFFFF0000u);
                C0 += h * w2;
                h.x = __uint_as_float(r2.y << 16); h.y = __uint_as_float(r2.y & 0xFFFF0000u);
                C1 += h * w2;
                h.x = __uint_as_float(r3.x << 16); h.y = __uint_as_float(r3.x & 0xFFFF0000u);
                D0 += h * w3;
                h.x = __uint_as_float(r3.y << 16); h.y = __uint_as_float(r3.y & 0xFFFF0000u);
                D1 += h * w3;
            }
        }
        f32x2 U0 = (A0 + B0) + (C0 + D0);
        f32x2 U1 = (A1 + B1) + (C1 + D1);
        float u0 = U0.x, u1 = U0.y, u2 = U1.x, u3 = U1.y;
        u0 += __shfl_xor(u0, 16, 64);
        u1 += __shfl_xor(u1, 16, 64);
        u2 += __shfl_xor(u2, 16, 64);
        u3 += __shfl_xor(u3, 16, 64);
        if (hl < 16) {
            float4 o4 = *reinterpret_cast<float4*>(out + (size_t)n * 64 + cid * 4);
            o4.x += u0; o4.y += u1; o4.z += u2; o4.w += u3;
            *reinterpret_cast<float4*>(out + (size_t)n * 64 + cid * 4) = o4;
        }
    }
}

// ---------------------------------------------------------------------------
extern "C" void kernel_launch(void* const* d_in, const int* in_sizes, int n_in,
                              void* d_out, int out_size, void* d_ws, size_t ws_size,
                              hipStream_t stream)
{
    const float* feat = (const float*)d_in[0];
    const float* Wg   = (const float*)d_in[1];
    const float* bg   = (const float*)d_in[2];
    const float* as_  = (const float*)d_in[3];
    const float* ad_  = (const float*)d_in[4];
    const float* Wp   = (const float*)d_in[5];
    const float* bp   = (const float*)d_in[6];
    const float* pv   = (const float*)d_in[7];
    const int*   lu   = (const int*)d_in[8];
    const int*   ld   = (const int*)d_in[9];
    const int*   pi   = (const int*)d_in[10];
    float* out = (float*)d_out;

    unsigned short* h16  = (unsigned short*)d_ws;        // NN*64 ushort
    unsigned short* hp16 = h16 + (size_t)NN * 64;        // NN*64 ushort
    float* fbase = (float*)(hp16 + (size_t)NN * 64);
    float* ssrc  = fbase;                                // NN
    float* sdst  = ssrc + NN;                            // NN
    int*   poff  = (int*)(sdst + NN);                    // 3*NN packed (start<<8|deg)
    int*   cnt   = poff + 3 * NN;                        // 3*NBK*16 (64B-padded)
    unsigned* bglu = (unsigned*)(cnt + 3 * NBK * 16);    // NBK*CAPB
    unsigned* bgld = bglu + (size_t)NBK * CAPB;          // NBK*CAPB
    unsigned* bgpc = bgld + (size_t)NBK * CAPB;          // NBK*CAPB
    unsigned short* bgpv = (unsigned short*)(bgpc + (size_t)NBK * CAPB); // NBK*CAPB us

    hipMemsetAsync(cnt, 0, (size_t)(3 * NBK * 16) * sizeof(int), stream);
    hipLaunchKernelGGL(k_gb, dim3(3 * NT + GEMM_BLKS), dim3(512), 0, stream,
                       feat, Wg, bg, as_, ad_, Wp, bp, h16, hp16, ssrc, sdst,
                       lu, ld, pi, pv, cnt, bglu, bgld, bgpc, bgpv);
    hipLaunchKernelGGL(k_b2c, dim3(3 * NBK), dim3(512), 0, stream,
                       cnt, bglu, bgld, bgpc, bgpv, ssrc, sdst, poff);
    hipLaunchKernelGGL(k_ggat, dim3(2048), dim3(256), 0, stream,
                       poff, bglu, bgld, h16, out);
    hipLaunchKernelGGL(k_gp, dim3(2048), dim3(256), 0, stream,
                       poff, bgpc, hp16, out);
}